// Round 17
// baseline (347001.172 us; speedup 1.0000x reference)
//
#include <hip/hip_runtime.h>
#include <cstddef>

// Problem constants
#define Tt 512
#define Ii 256
#define Hh 512
#define G4c 2048
#define SPIN_CAP 30000000
#define PRE_CAP  5000000

typedef float    f32x4 __attribute__((ext_vector_type(4)));
typedef _Float16 f16x8 __attribute__((ext_vector_type(8)));
typedef unsigned int u32x4 __attribute__((ext_vector_type(4)));

// ws layout (bytes) — END <= 8159744 (proven-safe bound)
#define OFF_WT1 0u
#define OFF_WT2 3145728u
#define OFF_BC1 7340032u
#define OFF_BC2 7348224u
#define OFF_H1G 7356416u          // [4 rh][2 slot][32*512] f16 cross-layer h1 (sc01)
#define OFF_H1L 7618560u          // [4 rh][2 slot][32*512] f16 local h1 (sc0 in LM)
#define OFF_H2L 7880704u          // [4 rh][2 slot][32*512] f16 local h2
#define OFF_FLGL 8142848u         // [8 g][32] u32, stride 8 (32B) — local flags
#define OFF_FLGG 8151040u         // [8 g][32] u32 compact — global flags
#define OFF_CTL  8152064u         // 6144 B control
#define OFF_END  8158208u
// CTL u32-word offsets
#define CW_XCC   0
#define CW_SLOT  256
#define CW_ARR   512
#define CW_RDY   520
#define CW_VOTE  544   // [8][32]
#define CW_GMODE 800   // [8] stride 8
#define CW_PROBE 864   // [8][32] stride 1 (sc0 probe words)

#define MFMA(a,b,c) __builtin_amdgcn_mfma_f32_16x16x32_f16((a),(b),(c),0,0,0)

__device__ __forceinline__ float sigm(float x)  { return 1.0f / (1.0f + __expf(-x)); }
__device__ __forceinline__ float tanhf_(float x){ return 1.0f - 2.0f / (1.0f + __expf(2.0f * x)); }

// ---- memory ops ----
__device__ __forceinline__ void ld_g_f16x8_sc(f16x8& d, const _Float16* p) {
  asm volatile("global_load_dwordx4 %0, %1, off sc0 sc1" : "=v"(d) : "v"(p) : "memory");
}
__device__ __forceinline__ void ld_g_f16x8_l(f16x8& d, const _Float16* p) {
  asm volatile("global_load_dwordx4 %0, %1, off sc0" : "=v"(d) : "v"(p) : "memory");
}
__device__ __forceinline__ void ld_g_f32x4(f32x4& d, const float* p) {
  asm volatile("global_load_dwordx4 %0, %1, off" : "=v"(d) : "v"(p) : "memory");
}
__device__ __forceinline__ void st32_sc01(void* p, unsigned v) {
  asm volatile("global_store_dword %0, %1, off sc0 sc1" :: "v"(p), "v"(v) : "memory");
}
__device__ __forceinline__ void st32_sc0(void* p, unsigned v) {
  asm volatile("global_store_dword %0, %1, off sc0" :: "v"(p), "v"(v) : "memory");
}
__device__ __forceinline__ void wait_vm0() {
  asm volatile("s_waitcnt vmcnt(0)" ::: "memory");
}
__device__ __forceinline__ void l1_inv() {          // L1-only invalidate (cheap)
  asm volatile("buffer_inv" ::: "memory");
}
__device__ __forceinline__ unsigned ldflag_sc01(const unsigned* p) {
  unsigned v;
  asm volatile("global_load_dword %0, %1, off sc0 sc1\n\ts_waitcnt vmcnt(0)"
               : "=v"(v) : "v"(p) : "memory");
  return v;
}
__device__ __forceinline__ unsigned ldflag_sc0(const unsigned* p) {
  unsigned v;
  asm volatile("global_load_dword %0, %1, off sc0\n\ts_waitcnt vmcnt(0)"
               : "=v"(v) : "v"(p) : "memory");
  return v;
}
__device__ __forceinline__ unsigned packh(float a, float b) {
  unsigned short ua = __builtin_bit_cast(unsigned short, (_Float16)a);
  unsigned short ub = __builtin_bit_cast(unsigned short, (_Float16)b);
  return (unsigned)ua | ((unsigned)ub << 16);
}

// Dual poll, r16 schedule. Own-group flags: LM -> local lines with per-iter
// L1-invalidate (sc0); else compact global (sc01). Peer: always global sc01.
template<bool LM>
__device__ __forceinline__ void pollstep(unsigned* ownl, unsigned* owng,
                                         unsigned* peerg, int* s_abort, int tid,
                                         unsigned tl, unsigned tp) {
  if (tid < 64) {
    const unsigned tgt = (tid < 32) ? tl : tp;
    unsigned v; int guard = 0;
    do {
      if (LM) l1_inv();
      if (tid < 32) v = LM ? ldflag_sc0(ownl + (size_t)tid * 8)
                           : ldflag_sc01(owng + tid);
      else          v = ldflag_sc01(peerg + (tid - 32));
      if (++guard > SPIN_CAP) { if (tid == 0) *s_abort = 1; break; }
    } while (__any(v < tgt));
  }
  __syncthreads();
}

// Publish: drain stores, block-sync, dual flag store (local sc0 + global sc01).
__device__ __forceinline__ void publish(unsigned* myfl_l, unsigned* myfl_g,
                                        int tid, unsigned val) {
  wait_vm0();
  __syncthreads();
  if (tid == 0) {
    st32_sc0(myfl_l, val);
    st32_sc01(myfl_g, val);
  }
}

// Pack weights FRAGMENT-MAJOR (rounds 5/7/10/12/16 proven)
__global__ void init_weights(const float* __restrict__ Wx1, const float* __restrict__ Wh1,
                             const float* __restrict__ bx1, const float* __restrict__ bh1,
                             const float* __restrict__ Wx2, const float* __restrict__ Wh2,
                             const float* __restrict__ bx2, const float* __restrict__ bh2,
                             _Float16* __restrict__ Wt1, _Float16* __restrict__ Wt2,
                             float* __restrict__ bc1, float* __restrict__ bc2) {
  const int b = blockIdx.x;
  const int layer = b >> 11;
  const int jb = (b >> 6) & 31;
  const int ln = b & 63;
  const int t  = threadIdx.x;
  const int ks = t >> 3;
  const int i  = t & 7;
  const int k  = (ks << 5) + ((ln >> 4) << 3) + i;
  if (layer == 0) {
    if (ln == 0 && t < 16) {
      #pragma unroll
      for (int g = 0; g < 4; ++g) {
        const int gc = (g << 9) + (jb << 4) + t;
        bc1[gc] = bx1[gc] + bh1[gc];
      }
    }
    if (ks < 24) {
      #pragma unroll
      for (int g = 0; g < 4; ++g) {
        const int gc = (g << 9) + (jb << 4) + (ln & 15);
        const float v = (k < Ii) ? Wx1[k * G4c + gc] : Wh1[(k - Ii) * G4c + gc];
        Wt1[((((size_t)jb * 24 + ks) * 4 + g) * 64 + ln) * 8 + i] = (_Float16)v;
      }
    }
  } else {
    if (ln == 0 && t < 16) {
      #pragma unroll
      for (int g = 0; g < 4; ++g) {
        const int gc = (g << 9) + (jb << 4) + t;
        bc2[gc] = bx2[gc] + bh2[gc];
      }
    }
    #pragma unroll
    for (int g = 0; g < 4; ++g) {
      const int gc = (g << 9) + (jb << 4) + (ln & 15);
      const float v = (k < Hh) ? Wx2[k * G4c + gc] : Wh2[(k - Hh) * G4c + gc];
      Wt2[((((size_t)jb * 32 + ks) * 4 + g) * 64 + ln) * 8 + i] = (_Float16)v;
    }
  }
}

__global__ void zero_ws(u32x4* p, int n) {
  const int i = blockIdx.x * blockDim.x + threadIdx.x;
  if (i < n) p[i] = (u32x4){0u, 0u, 0u, 0u};
}

// Main step loop — r16-green schedule, templated transport.
// L1@t: own>=t && peer(L2)>=t-1 ; L2@t: own>=t && peer(L1)>=t+1.
template<bool LM>
__device__ void mainloop(const float* __restrict__ x, const char* smem, f32x4* gxs,
                         int* s_abort, char* ws, int layer, int rh, int jb, int g,
                         int tid, const float* bcL, const float* __restrict__ Whead,
                         const float* __restrict__ bhead, float* __restrict__ out) {
  const int lane = tid & 63;
  const int wv = tid >> 6;
  const int rt = wv & 1;
  const int u  = wv >> 1;
  const int c15 = lane & 15;
  const int kg  = lane >> 4;
  const int j0 = jb << 4;
  const int lb = lane << 4;

  _Float16* h1g = (_Float16*)(ws + OFF_H1G) + (size_t)rh * 2 * 16384;
  _Float16* h1l = LM ? ((_Float16*)(ws + OFF_H1L) + (size_t)rh * 2 * 16384) : h1g;
  _Float16* h2l = (_Float16*)(ws + OFF_H2L) + (size_t)rh * 2 * 16384;
  unsigned* flgl = (unsigned*)(ws + OFF_FLGL);
  unsigned* flgg = (unsigned*)(ws + OFF_FLGG);
  unsigned* ownl  = flgl + (size_t)(g << 5) * 8;
  unsigned* owng  = flgg + (size_t)(g << 5);
  unsigned* peerg = flgg + (size_t)((g ^ 1) << 5);
  unsigned* myfl_l = ownl + (size_t)jb * 8;
  unsigned* myfl_g = owng + jb;

  const int browA = rh * 32 + rt * 16 + c15;
  const int arowl = rt * 16 + c15;

  const int erow = tid >> 3;
  const int col2 = (tid & 7) << 1;
  const int ert = erow >> 4, er15 = erow & 15;
  float bi_[4][2];
  #pragma unroll
  for (int gg = 0; gg < 4; ++gg) {
    bi_[gg][0] = bcL[(gg << 9) + j0 + col2];
    bi_[gg][1] = bcL[(gg << 9) + j0 + col2 + 1];
  }
  float cst0 = 0.f, cst1 = 0.f;
  const size_t eo = (size_t)erow * 512 + j0 + col2;

  for (int t = 0; t < Tt; ++t) {
    f32x4 a0 = {0.f,0.f,0.f,0.f}, a1 = {0.f,0.f,0.f,0.f};
    if (layer == 0) {
      f32x4 xf[16];
      const float* xp = x + ((size_t)browA * Tt + t) * Ii + (kg << 3);
      #pragma unroll
      for (int ks = 0; ks < 8; ++ks) {
        ld_g_f32x4(xf[2 * ks],     xp + (ks << 5));
        ld_g_f32x4(xf[2 * ks + 1], xp + (ks << 5) + 4);
      }
      pollstep<LM>(ownl, owng, peerg, s_abort, tid,
                   (unsigned)t, (t >= 1) ? (unsigned)(t - 1) : 0u);
      if (*s_abort) return;
      f16x8 af[24];
      if (t > 0) {
        const _Float16* hp = h1l + (size_t)((t - 1) & 1) * 16384
                             + (size_t)arowl * 512 + (kg << 3);
        #pragma unroll
        for (int ks = 0; ks < 16; ++ks) {
          if (LM) ld_g_f16x8_l(af[8 + ks], hp + (ks << 5));
          else    ld_g_f16x8_sc(af[8 + ks], hp + (ks << 5));
        }
      } else {
        #pragma unroll
        for (int ks = 0; ks < 16; ++ks)
          #pragma unroll
          for (int q = 0; q < 8; ++q) af[8 + ks][q] = (_Float16)0.f;
      }
      wait_vm0();
      __builtin_amdgcn_sched_barrier(0);
      #pragma unroll
      for (int ks = 0; ks < 8; ++ks) {
        f16x8 v;
        v[0] = (_Float16)xf[2*ks][0]; v[1] = (_Float16)xf[2*ks][1];
        v[2] = (_Float16)xf[2*ks][2]; v[3] = (_Float16)xf[2*ks][3];
        v[4] = (_Float16)xf[2*ks+1][0]; v[5] = (_Float16)xf[2*ks+1][1];
        v[6] = (_Float16)xf[2*ks+1][2]; v[7] = (_Float16)xf[2*ks+1][3];
        af[ks] = v;
      }
      #pragma unroll
      for (int ks = 0; ks < 24; ++ks) {
        const char* bp = smem + (ks << 12) + (u << 11) + lb;
        a0 = MFMA(af[ks], *(const f16x8*)(bp), a0);
        a1 = MFMA(af[ks], *(const f16x8*)(bp + 1024), a1);
      }
    } else {
      pollstep<LM>(ownl, owng, peerg, s_abort, tid, (unsigned)t, (unsigned)(t + 1));
      if (*s_abort) return;
      f16x8 af[32];
      const _Float16* h1p = h1g + (size_t)(t & 1) * 16384
                            + (size_t)arowl * 512 + (kg << 3);
      #pragma unroll
      for (int ks = 0; ks < 16; ++ks)
        ld_g_f16x8_sc(af[ks], h1p + (ks << 5));   // cross-layer: always sc01
      if (t > 0) {
        const _Float16* h2p = h2l + (size_t)((t - 1) & 1) * 16384
                              + (size_t)arowl * 512 + (kg << 3);
        #pragma unroll
        for (int ks = 0; ks < 16; ++ks) {
          if (LM) ld_g_f16x8_l(af[16 + ks], h2p + (ks << 5));
          else    ld_g_f16x8_sc(af[16 + ks], h2p + (ks << 5));
        }
      } else {
        #pragma unroll
        for (int ks = 0; ks < 16; ++ks)
          #pragma unroll
          for (int q = 0; q < 8; ++q) af[16 + ks][q] = (_Float16)0.f;
      }
      wait_vm0();
      __builtin_amdgcn_sched_barrier(0);
      #pragma unroll
      for (int ks = 0; ks < 32; ++ks) {
        const char* bp = smem + (ks << 12) + (u << 11) + lb;
        a0 = MFMA(af[ks], *(const f16x8*)(bp), a0);
        a1 = MFMA(af[ks], *(const f16x8*)(bp + 1024), a1);
      }
    }

    gxs[((rt * 4 + 2 * u)     * 16 + c15) * 4 + kg] = a0;
    gxs[((rt * 4 + 2 * u + 1) * 16 + c15) * 4 + kg] = a1;
    __syncthreads();

    const float* gb = (const float*)gxs;
    const int f0 = (ert * 4) * 256 + col2 * 16 + er15;
    const int f1 = f0 + 16;
    const float i0 = sigm (gb[f0      ] + bi_[0][0]);
    const float fv0= sigm (gb[f0 + 256] + bi_[1][0]);
    const float g0 = tanhf_(gb[f0 + 512] + bi_[2][0]);
    const float o0 = sigm (gb[f0 + 768] + bi_[3][0]);
    const float i1 = sigm (gb[f1      ] + bi_[0][1]);
    const float fv1= sigm (gb[f1 + 256] + bi_[1][1]);
    const float g1 = tanhf_(gb[f1 + 512] + bi_[2][1]);
    const float o1 = sigm (gb[f1 + 768] + bi_[3][1]);
    const float cv0 = fv0 * cst0 + i0 * g0; cst0 = cv0;
    const float cv1 = fv1 * cst1 + i1 * g1; cst1 = cv1;
    const unsigned hu = packh(o0 * tanhf_(cv0), o1 * tanhf_(cv1));

    if (layer == 0) {
      if (LM) st32_sc0((char*)(h1l + (size_t)(t & 1) * 16384 + eo), hu);
      st32_sc01((char*)(h1g + (size_t)(t & 1) * 16384 + eo), hu);
    } else {
      if (LM) st32_sc0((char*)(h2l + (size_t)(t & 1) * 16384 + eo), hu);
      else    st32_sc01((char*)(h2l + (size_t)(t & 1) * 16384 + eo), hu);
    }
    __syncthreads();
    publish(myfl_l, myfl_g, tid, (unsigned)(t + 1));
  }

  // head: L2 jb0 reads own group's h2l slot 1
  if (layer == 1 && jb == 0) {
    pollstep<LM>(ownl, owng, peerg, s_abort, tid, (unsigned)Tt, 0u);
    if (*s_abort) return;
    if (LM) l1_inv();
    if (tid < 128) {
      const int row = tid >> 2;
      const int cc = tid & 3;
      const _Float16* hr = h2l + 16384 + (size_t)row * 512;
      float s = bhead[cc];
      #pragma unroll
      for (int half = 0; half < 4; ++half) {
        f16x8 hv[16];
        #pragma unroll
        for (int j = 0; j < 16; ++j) {
          if (LM) ld_g_f16x8_l(hv[j], hr + (half << 7) + (j << 3));
          else    ld_g_f16x8_sc(hv[j], hr + (half << 7) + (j << 3));
        }
        wait_vm0();
        #pragma unroll
        for (int j = 0; j < 16; ++j) {
          const int k = (half << 7) + (j << 3);
          #pragma unroll
          for (int e = 0; e < 8; ++e)
            s += (float)hv[j][e] * Whead[(k + e) * 4 + cc];
        }
      }
      out[(rh * 32 + row) * 4 + cc] = s;
    }
  }
}

__global__ __launch_bounds__(256, 1) void lstm_main(
    const float* __restrict__ x,
    const _Float16* __restrict__ Wt1, const _Float16* __restrict__ Wt2,
    const float* __restrict__ bc1, const float* __restrict__ bc2,
    char* ws, const float* __restrict__ Whead, const float* __restrict__ bhead,
    float* __restrict__ out)
{
  extern __shared__ char smem[];
  __shared__ f32x4 gxs[512];
  __shared__ int sh_g, sh_jb, sh_lmc, sh_lm, s_abort;

  const int tid = threadIdx.x;
  unsigned* ctl = (unsigned*)(((char*)ws) + OFF_CTL);
  if (tid == 0) s_abort = 0;

  // ---- Phase 1: single-writer XCD role assignment (block 0 decides) ----
  if (tid == 0) {
    unsigned xcc;
    asm volatile("s_getreg_b32 %0, hwreg(HW_REG_XCC_ID)" : "=s"(xcc));
    xcc &= 7u;
    st32_sc01(ctl + CW_XCC + blockIdx.x, xcc + 1u);
    wait_vm0();
    __hip_atomic_fetch_add((int*)(ctl + CW_ARR), 1, __ATOMIC_RELAXED,
                           __HIP_MEMORY_SCOPE_AGENT);
    if (blockIdx.x == 0) {
      int guard = 0;
      while (__hip_atomic_load((int*)(ctl + CW_ARR), __ATOMIC_RELAXED,
                               __HIP_MEMORY_SCOPE_AGENT) < 256) {
        if (++guard > SPIN_CAP) break;
      }
      unsigned cnt[8] = {0,0,0,0,0,0,0,0};
      bool ok = (guard <= SPIN_CAP);
      for (int i = 0; i < 256 && ok; ++i) {
        const unsigned xv = ldflag_sc01(ctl + CW_XCC + i);
        if (xv == 0 || xv > 8) { ok = false; break; }
        st32_sc01(ctl + CW_SLOT + i, cnt[xv - 1]++);
      }
      #pragma unroll
      for (int i = 0; i < 8; ++i) ok = ok && (cnt[i] == 32);
      wait_vm0();
      st32_sc01(ctl + CW_RDY, ok ? 2u : 1u);
    }
    unsigned rv; int guard = 0;
    do {
      rv = ldflag_sc01(ctl + CW_RDY);
      if (++guard > SPIN_CAP) { rv = 1u; break; }
    } while (rv == 0);
    sh_lmc = (rv == 2);
    if (sh_lmc) {
      sh_g  = (int)(ldflag_sc01(ctl + CW_XCC + blockIdx.x) - 1u);
      sh_jb = (int)ldflag_sc01(ctl + CW_SLOT + blockIdx.x);
    } else {
      sh_g  = (int)(blockIdx.x >> 5);
      sh_jb = (int)(blockIdx.x & 31);
    }
  }
  __syncthreads();
  const int g = sh_g, jb = sh_jb;
  const int layer = g & 1, rh = g >> 1;

  // ---- Phase 2: preflight — REPEATED inv+sc0 polls (the exact mainloop
  // pattern that stalled r13/r14); per-group sc01 vote ----
  if (tid == 0) sh_lm = 0;
  __syncthreads();
  if (sh_lmc) {
    int okp = 1;
    for (int r = 1; r <= 3 && okp; ++r) {
      if (tid == 0) st32_sc0(ctl + CW_PROBE + (g << 5) + jb, (unsigned)r);
      if (tid < 32) {
        unsigned v; int guard = 0;
        do {
          l1_inv();
          v = ldflag_sc0(ctl + CW_PROBE + (g << 5) + tid);
          if (++guard > PRE_CAP) { okp = 0; break; }
        } while (__any(v < (unsigned)r) && okp);
      }
      __syncthreads();
      okp = __syncthreads_and(okp);
    }
    if (tid == 0) st32_sc01(ctl + CW_VOTE + (g << 5) + jb, okp ? 2u : 1u);
    if (jb == 0 && tid < 32) {
      unsigned v; int guard = 0;
      do {
        v = ldflag_sc01(ctl + CW_VOTE + (g << 5) + tid);
        if (++guard > SPIN_CAP) { v = 1u; break; }
      } while (v < 1u);
      const int allok = __all(v == 2u);
      if (tid == 0) st32_sc01(ctl + CW_GMODE + (g << 3), allok ? 2u : 1u);
    }
    if (tid == 0) {
      unsigned v; int guard = 0;
      do {
        v = ldflag_sc01(ctl + CW_GMODE + (g << 3));
        if (++guard > SPIN_CAP) { v = 1u; break; }
      } while (v == 0u);
      sh_lm = (v == 2u);
    }
    __syncthreads();
  }
  const int lm = sh_lm;

  // ---- stage fragment-major weight slice into LDS ----
  {
    const int elems16 = layer ? (131072 / 16) : (98304 / 16);
    const u32x4* src = (const u32x4*)((layer ? Wt2 : Wt1)
                                      + (size_t)jb * (layer ? 65536 : 49152));
    u32x4* dst = (u32x4*)smem;
    for (int i = tid; i < elems16; i += 256) dst[i] = src[i];
  }
  __syncthreads();

  const float* bcL = layer ? bc2 : bc1;
  if (lm) mainloop<true >(x, smem, gxs, &s_abort, ws, layer, rh, jb, g, tid, bcL, Whead, bhead, out);
  else    mainloop<false>(x, smem, gxs, &s_abort, ws, layer, rh, jb, g, tid, bcL, Whead, bhead, out);
}

extern "C" void kernel_launch(void* const* d_in, const int* in_sizes, int n_in,
                              void* d_out, int out_size, void* d_ws, size_t ws_size,
                              hipStream_t stream) {
  const float* x   = (const float*)d_in[0];
  const float* Wx1 = (const float*)d_in[1];
  const float* bx1 = (const float*)d_in[2];
  const float* Wh1 = (const float*)d_in[3];
  const float* bh1 = (const float*)d_in[4];
  const float* Wx2 = (const float*)d_in[5];
  const float* bx2 = (const float*)d_in[6];
  const float* Wh2 = (const float*)d_in[7];
  const float* bh2 = (const float*)d_in[8];
  const float* Whd = (const float*)d_in[9];
  const float* bhd = (const float*)d_in[10];

  char* ws = (char*)d_ws;
  _Float16* Wt1 = (_Float16*)(ws + OFF_WT1);
  _Float16* Wt2 = (_Float16*)(ws + OFF_WT2);
  float* bc1 = (float*)(ws + OFF_BC1);
  float* bc2 = (float*)(ws + OFF_BC2);
  float* out = (float*)d_out;

  init_weights<<<4096, 256, 0, stream>>>(Wx1, Wh1, bx1, bh1, Wx2, Wh2, bx2, bh2,
                                         Wt1, Wt2, bc1, bc2);
  {
    u32x4* zp = (u32x4*)(ws + OFF_H1G);
    const int n = (int)((OFF_END - OFF_H1G) / 16);  // rings + flags + ctl
    zero_ws<<<(n + 255) / 256, 256, 0, stream>>>(zp, n);
  }
  (void)hipFuncSetAttribute((const void*)lstm_main,
                            hipFuncAttributeMaxDynamicSharedMemorySize, 131072);
  void* args[] = {(void*)&x, (void*)&Wt1, (void*)&Wt2, (void*)&bc1, (void*)&bc2,
                  (void*)&ws, (void*)&Whd, (void*)&bhd, (void*)&out};
  hipError_t err = hipLaunchCooperativeKernel((const void*)lstm_main, dim3(256),
                                              dim3(256), args, 131072, stream);
  if (err != hipSuccess) {
    lstm_main<<<dim3(256), dim3(256), 131072, stream>>>(
        x, Wt1, Wt2, bc1, bc2, ws, Whd, bhd, out);
  }
}

// Round 18
// 3549.774 us; speedup vs baseline: 97.7530x; 97.7530x over previous
//
#include <hip/hip_runtime.h>
#include <cstddef>

// Problem constants
#define Tt 512
#define Ii 256
#define Hh 512
#define G4c 2048
#define FSTRIDE 32        // u32 per flag (128B line)
#define SPIN_CAP 50000000

typedef float    f32x4 __attribute__((ext_vector_type(4)));
typedef _Float16 f16x8 __attribute__((ext_vector_type(8)));
typedef unsigned int u32x4 __attribute__((ext_vector_type(4)));

// ws layout (bytes) — END <= 8159744 (proven-safe bound)
#define OFF_WT1 0u
#define OFF_WT2 3145728u          // 32jb*24ks*4g*64ln*8i*2B
#define OFF_BC1 7340032u          // +32jb*32ks*4g*64ln*8i*2B
#define OFF_BC2 7348224u
#define OFF_H1  7356416u          // [4 rh][2 slot][32*512] f16 = 262144
#define OFF_H2  7618560u          // [4 rh][2 slot][32*512] f16 = 262144
#define OFF_FLG 7880704u          // [8 g][32 jb] * 128B = 32768
#define OFF_END 7913472u

#define MFMA(a,b,c) __builtin_amdgcn_mfma_f32_16x16x32_f16((a),(b),(c),0,0,0)

__device__ __forceinline__ float sigm(float x)  { return 1.0f / (1.0f + __expf(-x)); }
__device__ __forceinline__ float tanhf_(float x){ return 1.0f - 2.0f / (1.0f + __expf(2.0f * x)); }

// ---- coherent (cross-XCD) memory ops (green-proven family) ----
__device__ __forceinline__ void ld_g_f16x8_sc(f16x8& dst, const _Float16* p) {
  asm volatile("global_load_dwordx4 %0, %1, off sc0 sc1"
               : "=v"(dst) : "v"(p) : "memory");
}
__device__ __forceinline__ void ld_g_f32x4(f32x4& dst, const float* p) {
  asm volatile("global_load_dwordx4 %0, %1, off" : "=v"(dst) : "v"(p) : "memory");
}
__device__ __forceinline__ void st_g_u32_sc(void* p, unsigned v) {
  asm volatile("global_store_dword %0, %1, off sc0 sc1" :: "v"(p), "v"(v) : "memory");
}
__device__ __forceinline__ void wait_vm0() {
  asm volatile("s_waitcnt vmcnt(0)" ::: "memory");
}
__device__ __forceinline__ unsigned packh(float a, float b) {
  unsigned short ua = __builtin_bit_cast(unsigned short, (_Float16)a);
  unsigned short ub = __builtin_bit_cast(unsigned short, (_Float16)b);
  return (unsigned)ua | ((unsigned)ub << 16);
}

// Direct dual poll (r7/r16-proven fastest): lanes 0-31 watch own-group member
// flags vs tl; lanes 32-63 watch peer-group member flags vs tp. Capped.
__device__ __forceinline__ void pollstep(unsigned* own, unsigned* peer,
                                         int* s_abort, int tid,
                                         unsigned tl, unsigned tp) {
  if (tid < 64) {
    const unsigned tgt = (tid < 32) ? tl : tp;
    const unsigned* p = (tid < 32) ? own + (size_t)tid * FSTRIDE
                                   : peer + (size_t)(tid - 32) * FSTRIDE;
    unsigned v; int guard = 0;
    do {
      v = __hip_atomic_load(p, __ATOMIC_RELAXED, __HIP_MEMORY_SCOPE_AGENT);
      if (++guard > SPIN_CAP) { if (tid == 0) *s_abort = 1; break; }
    } while (__any(v < tgt));
  }
  __syncthreads();
}

// Publish: drain own sc stores (per-wave), block-sync, set own flag.
__device__ __forceinline__ void publish(unsigned* myflag, int tid, unsigned val) {
  wait_vm0();
  __syncthreads();
  if (tid == 0)
    __hip_atomic_store(myflag, val, __ATOMIC_RELAXED, __HIP_MEMORY_SCOPE_AGENT);
}

// Pack weights FRAGMENT-MAJOR (rounds 5/7/10/12/16 proven): WtF[jb][ks][g][lane][i] =
//   W_cat[k = ks*32 + (lane>>4)*8 + i][gcol = g*512 + jb*16 + (lane&15)]
__global__ void init_weights(const float* __restrict__ Wx1, const float* __restrict__ Wh1,
                             const float* __restrict__ bx1, const float* __restrict__ bh1,
                             const float* __restrict__ Wx2, const float* __restrict__ Wh2,
                             const float* __restrict__ bx2, const float* __restrict__ bh2,
                             _Float16* __restrict__ Wt1, _Float16* __restrict__ Wt2,
                             float* __restrict__ bc1, float* __restrict__ bc2) {
  const int b = blockIdx.x;
  const int layer = b >> 11;
  const int jb = (b >> 6) & 31;
  const int ln = b & 63;
  const int t  = threadIdx.x;
  const int ks = t >> 3;
  const int i  = t & 7;
  const int k  = (ks << 5) + ((ln >> 4) << 3) + i;
  if (layer == 0) {
    if (ln == 0 && t < 16) {
      #pragma unroll
      for (int g = 0; g < 4; ++g) {
        const int gc = (g << 9) + (jb << 4) + t;
        bc1[gc] = bx1[gc] + bh1[gc];
      }
    }
    if (ks < 24) {
      #pragma unroll
      for (int g = 0; g < 4; ++g) {
        const int gc = (g << 9) + (jb << 4) + (ln & 15);
        const float v = (k < Ii) ? Wx1[k * G4c + gc] : Wh1[(k - Ii) * G4c + gc];
        Wt1[((((size_t)jb * 24 + ks) * 4 + g) * 64 + ln) * 8 + i] = (_Float16)v;
      }
    }
  } else {
    if (ln == 0 && t < 16) {
      #pragma unroll
      for (int g = 0; g < 4; ++g) {
        const int gc = (g << 9) + (jb << 4) + t;
        bc2[gc] = bx2[gc] + bh2[gc];
      }
    }
    #pragma unroll
    for (int g = 0; g < 4; ++g) {
      const int gc = (g << 9) + (jb << 4) + (ln & 15);
      const float v = (k < Hh) ? Wx2[k * G4c + gc] : Wh2[(k - Hh) * G4c + gc];
      Wt2[((((size_t)jb * 32 + ks) * 4 + g) * 64 + ln) * 8 + i] = (_Float16)v;
    }
  }
}

__global__ void zero_ws(u32x4* p, int n) {
  const int i = blockIdx.x * blockDim.x + threadIdx.x;
  if (i < n) p[i] = (u32x4){0u, 0u, 0u, 0u};
}

// Persistent cooperative kernel: 256 blocks (1/CU), 8 groups of 32.
// g = bid>>5: layer = g&1, rh = g>>1 (batch rows rh*32..+31); jb = bid&31
// (16 H-cols). Per-block: 4 waves, 32 rows x 16 cols output.
// Flags [g][jb] = t+1 after finishing step t. Direct dual-poll schedule:
//   L1@t: own >= t (h1(t-1) ready) && peer(L2) >= t-1 (slot t&1 free)
//   L2@t: own >= t (h2(t-1) ready) && peer(L1) >= t+1 (h1(t) ready)
// Deadlock-free: t1<=t2 && t2<t1-1 is contradictory.
__global__ __launch_bounds__(256, 1) void lstm_main(
    const float* __restrict__ x,
    const _Float16* __restrict__ Wt1, const _Float16* __restrict__ Wt2,
    const float* __restrict__ bc1, const float* __restrict__ bc2,
    _Float16* h1buf, _Float16* h2buf, unsigned* flags,
    const float* __restrict__ Whead, const float* __restrict__ bhead,
    float* __restrict__ out)
{
  extern __shared__ char smem[];
  __shared__ f32x4 gxs[512];          // 8 KB gate exchange
  __shared__ int s_abort;

  const int tid  = threadIdx.x;
  const int lane = tid & 63;
  const int wv   = tid >> 6;
  const int bid  = blockIdx.x;
  const int g    = bid >> 5;
  const int jb   = bid & 31;
  const int layer = g & 1;
  const int rh    = g >> 1;
  const int j0 = jb << 4;
  if (tid == 0) s_abort = 0;

  unsigned* own  = flags + (size_t)(g << 5) * FSTRIDE;
  unsigned* peer = flags + (size_t)((g ^ 1) << 5) * FSTRIDE;
  unsigned* myfl = own + (size_t)jb * FSTRIDE;

  // ---- stage fragment-major weight slice into LDS (flat copy) ----
  {
    const int elems16 = layer ? (131072 / 16) : (98304 / 16);
    const u32x4* src = (const u32x4*)((layer ? Wt2 : Wt1)
                                      + (size_t)jb * (layer ? 65536 : 49152));
    u32x4* dst = (u32x4*)smem;
    for (int i = tid; i < elems16; i += 256) dst[i] = src[i];
  }
  __syncthreads();

  const int rt  = wv & 1;           // row-tile (16 rows)
  const int u   = wv >> 1;          // gate pair {2u, 2u+1}
  const int c15 = lane & 15;
  const int kg  = lane >> 4;
  const int lb  = lane << 4;

  _Float16* h1b = h1buf + (size_t)rh * 2 * 16384;
  _Float16* h2b = h2buf + (size_t)rh * 2 * 16384;
  const int browA = rh * 32 + rt * 16 + c15;   // global batch row for A frags
  const int arowl = rt * 16 + c15;             // row within group (0..31)

  // elementwise role: (row erow 0..31, col pair col2)
  const int erow = tid >> 3;
  const int col2 = (tid & 7) << 1;
  const int ert = erow >> 4, er15 = erow & 15;
  const float* bcL = layer ? bc2 : bc1;
  float bi_[4][2];
  #pragma unroll
  for (int gg = 0; gg < 4; ++gg) {
    bi_[gg][0] = bcL[(gg << 9) + j0 + col2];
    bi_[gg][1] = bcL[(gg << 9) + j0 + col2 + 1];
  }
  float cst0 = 0.f, cst1 = 0.f;
  const size_t eo = (size_t)erow * 512 + j0 + col2;   // offset in 32x512 buf

  for (int t = 0; t < Tt; ++t) {
    f32x4 a0 = {0.f,0.f,0.f,0.f}, a1 = {0.f,0.f,0.f,0.f};
    if (layer == 0) {
      // x prefetch before the wait (plain cached)
      f32x4 xf[16];
      const float* xp = x + ((size_t)browA * Tt + t) * Ii + (kg << 3);
      #pragma unroll
      for (int ks = 0; ks < 8; ++ks) {
        ld_g_f32x4(xf[2 * ks],     xp + (ks << 5));
        ld_g_f32x4(xf[2 * ks + 1], xp + (ks << 5) + 4);
      }
      pollstep(own, peer, &s_abort, tid,
               (unsigned)t, (t >= 1) ? (unsigned)(t - 1) : 0u);
      if (s_abort) return;
      f16x8 af[24];
      if (t > 0) {
        const _Float16* hp = h1b + (size_t)((t - 1) & 1) * 16384
                             + (size_t)arowl * 512 + (kg << 3);
        #pragma unroll
        for (int ks = 0; ks < 16; ++ks)
          ld_g_f16x8_sc(af[8 + ks], hp + (ks << 5));
      } else {
        #pragma unroll
        for (int ks = 0; ks < 16; ++ks)
          #pragma unroll
          for (int q = 0; q < 8; ++q) af[8 + ks][q] = (_Float16)0.f;
      }
      wait_vm0();
      __builtin_amdgcn_sched_barrier(0);
      #pragma unroll
      for (int ks = 0; ks < 8; ++ks) {
        f16x8 v;
        v[0] = (_Float16)xf[2*ks][0]; v[1] = (_Float16)xf[2*ks][1];
        v[2] = (_Float16)xf[2*ks][2]; v[3] = (_Float16)xf[2*ks][3];
        v[4] = (_Float16)xf[2*ks+1][0]; v[5] = (_Float16)xf[2*ks+1][1];
        v[6] = (_Float16)xf[2*ks+1][2]; v[7] = (_Float16)xf[2*ks+1][3];
        af[ks] = v;
      }
      #pragma unroll
      for (int ks = 0; ks < 24; ++ks) {
        const char* bp = smem + (ks << 12) + (u << 11) + lb;
        a0 = MFMA(af[ks], *(const f16x8*)(bp), a0);
        a1 = MFMA(af[ks], *(const f16x8*)(bp + 1024), a1);
      }
    } else {
      pollstep(own, peer, &s_abort, tid, (unsigned)t, (unsigned)(t + 1));
      if (s_abort) return;
      f16x8 af[32];
      const _Float16* h1p = h1b + (size_t)(t & 1) * 16384
                            + (size_t)arowl * 512 + (kg << 3);
      #pragma unroll
      for (int ks = 0; ks < 16; ++ks)
        ld_g_f16x8_sc(af[ks], h1p + (ks << 5));
      if (t > 0) {
        const _Float16* h2p = h2b + (size_t)((t - 1) & 1) * 16384
                              + (size_t)arowl * 512 + (kg << 3);
        #pragma unroll
        for (int ks = 0; ks < 16; ++ks)
          ld_g_f16x8_sc(af[16 + ks], h2p + (ks << 5));
      } else {
        #pragma unroll
        for (int ks = 0; ks < 16; ++ks)
          #pragma unroll
          for (int q = 0; q < 8; ++q) af[16 + ks][q] = (_Float16)0.f;
      }
      wait_vm0();
      __builtin_amdgcn_sched_barrier(0);
      #pragma unroll
      for (int ks = 0; ks < 32; ++ks) {
        const char* bp = smem + (ks << 12) + (u << 11) + lb;
        a0 = MFMA(af[ks], *(const f16x8*)(bp), a0);
        a1 = MFMA(af[ks], *(const f16x8*)(bp + 1024), a1);
      }
    }

    // gate exchange via LDS: float idx = (rt*4 + gate)*256 + col*16 + (kg*4+r)
    gxs[((rt * 4 + 2 * u)     * 16 + c15) * 4 + kg] = a0;
    gxs[((rt * 4 + 2 * u + 1) * 16 + c15) * 4 + kg] = a1;
    __syncthreads();

    const float* gb = (const float*)gxs;
    const int f0 = (ert * 4) * 256 + col2 * 16 + er15;
    const int f1 = f0 + 16;
    const float i0 = sigm (gb[f0      ] + bi_[0][0]);
    const float fv0= sigm (gb[f0 + 256] + bi_[1][0]);
    const float g0 = tanhf_(gb[f0 + 512] + bi_[2][0]);
    const float o0 = sigm (gb[f0 + 768] + bi_[3][0]);
    const float i1 = sigm (gb[f1      ] + bi_[0][1]);
    const float fv1= sigm (gb[f1 + 256] + bi_[1][1]);
    const float g1 = tanhf_(gb[f1 + 512] + bi_[2][1]);
    const float o1 = sigm (gb[f1 + 768] + bi_[3][1]);
    const float cv0 = fv0 * cst0 + i0 * g0; cst0 = cv0;
    const float cv1 = fv1 * cst1 + i1 * g1; cst1 = cv1;
    const unsigned hu = packh(o0 * tanhf_(cv0), o1 * tanhf_(cv1));

    _Float16* hw = (layer == 0) ? (h1b + (size_t)(t & 1) * 16384)
                                : (h2b + (size_t)(t & 1) * 16384);
    st_g_u32_sc((char*)(hw + eo), hu);
    __syncthreads();                 // gxs reuse guard before next epoch
    publish(myfl, tid, (unsigned)(t + 1));
  }

  // head: L2-group jb0 blocks; h2_T = h2 slot (511&1)=1
  if (layer == 1 && jb == 0) {
    pollstep(own, peer, &s_abort, tid, (unsigned)Tt, 0u);
    if (s_abort) return;
    if (tid < 128) {
      const int row = tid >> 2;
      const int cc = tid & 3;
      const _Float16* hr = h2b + 16384 + (size_t)row * 512;
      float s = bhead[cc];
      #pragma unroll
      for (int half = 0; half < 4; ++half) {
        f16x8 hv[16];
        #pragma unroll
        for (int j = 0; j < 16; ++j)
          ld_g_f16x8_sc(hv[j], hr + (half << 7) + (j << 3));
        wait_vm0();
        #pragma unroll
        for (int j = 0; j < 16; ++j) {
          const int k = (half << 7) + (j << 3);
          #pragma unroll
          for (int e = 0; e < 8; ++e)
            s += (float)hv[j][e] * Whead[(k + e) * 4 + cc];
        }
      }
      out[(rh * 32 + row) * 4 + cc] = s;
    }
  }
}

extern "C" void kernel_launch(void* const* d_in, const int* in_sizes, int n_in,
                              void* d_out, int out_size, void* d_ws, size_t ws_size,
                              hipStream_t stream) {
  const float* x   = (const float*)d_in[0];
  const float* Wx1 = (const float*)d_in[1];
  const float* bx1 = (const float*)d_in[2];
  const float* Wh1 = (const float*)d_in[3];
  const float* bh1 = (const float*)d_in[4];
  const float* Wx2 = (const float*)d_in[5];
  const float* bx2 = (const float*)d_in[6];
  const float* Wh2 = (const float*)d_in[7];
  const float* bh2 = (const float*)d_in[8];
  const float* Whd = (const float*)d_in[9];
  const float* bhd = (const float*)d_in[10];

  char* ws = (char*)d_ws;
  _Float16* Wt1 = (_Float16*)(ws + OFF_WT1);
  _Float16* Wt2 = (_Float16*)(ws + OFF_WT2);
  float* bc1 = (float*)(ws + OFF_BC1);
  float* bc2 = (float*)(ws + OFF_BC2);
  _Float16* h1b = (_Float16*)(ws + OFF_H1);
  _Float16* h2b = (_Float16*)(ws + OFF_H2);
  unsigned* flg = (unsigned*)(ws + OFF_FLG);
  float* out = (float*)d_out;

  init_weights<<<4096, 256, 0, stream>>>(Wx1, Wh1, bx1, bh1, Wx2, Wh2, bx2, bh2,
                                         Wt1, Wt2, bc1, bc2);
  {
    u32x4* zp = (u32x4*)(ws + OFF_H1);
    const int n = (int)((OFF_END - OFF_H1) / 16);  // h rings + flags
    zero_ws<<<(n + 255) / 256, 256, 0, stream>>>(zp, n);
  }
  (void)hipFuncSetAttribute((const void*)lstm_main,
                            hipFuncAttributeMaxDynamicSharedMemorySize, 131072);
  void* args[] = {(void*)&x, (void*)&Wt1, (void*)&Wt2, (void*)&bc1, (void*)&bc2,
                  (void*)&h1b, (void*)&h2b, (void*)&flg,
                  (void*)&Whd, (void*)&bhd, (void*)&out};
  (void)hipLaunchCooperativeKernel((const void*)lstm_main, dim3(256), dim3(256),
                                   args, 131072, stream);
}